// Round 4
// baseline (103.718 us; speedup 1.0000x reference)
//
#include <hip/hip_runtime.h>
#include <hip/hip_bf16.h>

#define B_    2
#define CIN   4
#define COUT  8
#define KK    4
#define DD    2
#define NN    224
#define FDIM  128
#define NH    218
#define NSUB  (NH*NH)         // 47524
#define NPERM 24
#define NROWS (B_*COUT*CIN)   // 64 softmax rows
#define NSUB4 (NSUB/4)        // 11881 float4s per row
#define CH4   512             // float4s per chunk (final transform)
#define MBF   ((NSUB4 + CH4 - 1) / CH4)   // 24 chunk-blocks per row (final)
#define OG    2               // o-split; each thread handles COUT/OG = 4 o's
#define NCHS  ((NSUB + 511) / 512)        // 93 s-chunks (512 s per sims block)
#define NEGBIG (-3.4e38f)

typedef float v2f __attribute__((ext_vector_type(2)));

__device__ static constexpr int PERM[NPERM][4] = {
  {0,1,2,3},{0,1,3,2},{0,2,1,3},{0,2,3,1},{0,3,1,2},{0,3,2,1},
  {1,0,2,3},{1,0,3,2},{1,2,0,3},{1,2,3,0},{1,3,0,2},{1,3,2,0},
  {2,0,1,3},{2,0,3,1},{2,1,0,3},{2,1,3,0},{2,3,0,1},{2,3,1,0},
  {3,0,1,2},{3,0,2,1},{3,1,0,2},{3,1,2,0},{3,2,0,1},{3,2,1,0}
};

// one wave per (b,f): lanes split r, shuffle-reduce
__global__ __launch_bounds__(64) void hmean_kernel(const float* __restrict__ features,
                                                   float* __restrict__ out) {
  int bf = blockIdx.x;
  int b = bf / FDIM, f = bf - b * FDIM;
  int lane = threadIdx.x;
  const float* fb = features + (size_t)b * NN * FDIM + f;
  float acc = 0.f;
  for (int r = lane; r < NN; r += 64) {
    int w = 0;
#pragma unroll
    for (int a = 0; a < KK; ++a) {
      int i0 = r - a * DD;
      if (0 <= i0 && i0 < NH) w++;
    }
    acc += (float)w * fb[(size_t)r * FDIM];
  }
#pragma unroll
  for (int off = 32; off > 0; off >>= 1) acc += __shfl_down(acc, off, 64);
  if (lane == 0) out[bf] = acc * (2.0f / (float)NH);
}

// grid: (NCHS, B*CIN*OG). Each thread: s0 = blk*512+t, s1 = s0+256, packed v2f.
// 4 o's via pair-DP perm loop. FUSED softmax partial stats: after computing
// each o-row's 512 values, block-reduce (max, sum-exp) and emit one
// (M,S) partial per (row, chunk) -> softmax_partial pass deleted.
__global__ __launch_bounds__(256, 2) void sims_kernel(
    const float* __restrict__ graph, const float* __restrict__ types,
    const float* __restrict__ ksA, const float* __restrict__ krA,
    const float* __restrict__ kcA, float* __restrict__ simsOut,
    float* __restrict__ partial)
{
  __shared__ float ls[COUT * CIN * 16];
  __shared__ float lr[COUT * CIN * 4];
  __shared__ float lc[COUT * CIN * 4];
  __shared__ float lK2[COUT * CIN];
  __shared__ float redM[4], redS[4];
  int t = threadIdx.x;
  for (int i = t; i < COUT * CIN * 16; i += 256) ls[i] = ksA[i];
  for (int i = t; i < COUT * CIN * 4; i += 256) { lr[i] = krA[i]; lc[i] = kcA[i]; }
  __syncthreads();
  if (t < COUT * CIN) {
    float k2 = 0.f;
#pragma unroll
    for (int u = 0; u < 16; ++u) k2 += ls[t * 16 + u] * ls[t * 16 + u];
#pragma unroll
    for (int u = 0; u < 4; ++u) k2 += lr[t * 4 + u] * lr[t * 4 + u] + lc[t * 4 + u] * lc[t * 4 + u];
    lK2[t] = k2;
  }
  __syncthreads();

  int s0r = blockIdx.x * 512 + t;
  int s1r = s0r + 256;
  bool v0 = (s0r < NSUB), v1 = (s1r < NSUB);
  int s0 = v0 ? s0r : (NSUB - 1);
  int s1 = v1 ? s1r : (NSUB - 1);
  int yi  = blockIdx.y;
  int og  = yi >> 3;
  int bci = yi & 7;
  int b   = bci >> 2;
  int ci  = bci & 3;
  int ii0 = s0 / NH, jj0 = s0 - ii0 * NH;
  int ii1 = s1 / NH, jj1 = s1 - ii1 * NH;

  int wave = t >> 6, lane = t & 63;

  const float* gi = graph + ((size_t)b * CIN + ci) * NN * NN;
  const float* ti = types + ((size_t)b * CIN + ci) * NN;

  v2f subv[16], rtv[4], ctv[4];
  v2f G2 = 0.f, T2r = 0.f, T2c = 0.f;
#pragma unroll
  for (int a = 0; a < KK; ++a) {
    const float* r0 = gi + (size_t)(ii0 + a * DD) * NN + jj0;
    const float* r1 = gi + (size_t)(ii1 + a * DD) * NN + jj1;
#pragma unroll
    for (int bb = 0; bb < KK; ++bb) {
      v2f v; v.x = r0[bb * DD]; v.y = r1[bb * DD];
      subv[a * 4 + bb] = v;
      G2 += v * v;
    }
    v2f rv; rv.x = ti[ii0 + a * DD]; rv.y = ti[ii1 + a * DD];
    v2f cv; cv.x = ti[jj0 + a * DD]; cv.y = ti[jj1 + a * DD];
    rtv[a] = rv; ctv[a] = cv;
    T2r += rv * rv; T2c += cv * cv;
  }
  v2f base0 = G2 + T2r + T2c;

#pragma unroll 1
  for (int oo = 0; oo < COUT / OG; ++oo) {
    int o = og * (COUT / OG) + oo;
    int oc = o * CIN + ci;
    float kS[16], kR[4], kC[4];
    {
      const float4* pS4 = (const float4*)(ls + oc * 16);
#pragma unroll
      for (int u = 0; u < 4; ++u) {
        float4 q = pS4[u];
        kS[u*4+0] = q.x; kS[u*4+1] = q.y; kS[u*4+2] = q.z; kS[u*4+3] = q.w;
      }
      float4 qr = *(const float4*)(lr + oc * 4);
      kR[0] = qr.x; kR[1] = qr.y; kR[2] = qr.z; kR[3] = qr.w;
      float4 qc = *(const float4*)(lc + oc * 4);
      kC[0] = qc.x; kC[1] = qc.y; kC[2] = qc.z; kC[3] = qc.w;
    }

    // C1[a][a'] = diag + row + col contribution for mapping a->a'
    v2f C1[16];
#pragma unroll
    for (int a = 0; a < 4; ++a)
#pragma unroll
      for (int ap = 0; ap < 4; ++ap)
        C1[a * 4 + ap] = subv[a * 4 + a] * kS[ap * 4 + ap]
                       + rtv[a] * kR[ap] + ctv[a] * kC[ap];

    // pair-DP: pair01[x][y] covers positions {0,1} -> (x,y); pair23 likewise.
    v2f pair01[16], pair23[16];
#pragma unroll
    for (int x = 0; x < 4; ++x)
#pragma unroll
      for (int y = 0; y < 4; ++y) {
        if (x == y) continue;
        pair01[x * 4 + y] = C1[0 * 4 + x] + C1[1 * 4 + y]
                          + subv[0*4+1] * kS[x*4+y] + subv[1*4+0] * kS[y*4+x];
        pair23[x * 4 + y] = C1[2 * 4 + x] + C1[3 * 4 + y]
                          + subv[2*4+3] * kS[x*4+y] + subv[3*4+2] * kS[y*4+x];
      }

    v2f maxcr = NEGBIG;
#pragma unroll
    for (int p = 0; p < NPERM; ++p) {
      const int p0 = PERM[p][0], p1 = PERM[p][1], p2 = PERM[p][2], p3 = PERM[p][3];
      v2f cr = pair01[p0 * 4 + p1] + pair23[p2 * 4 + p3];
      cr += subv[0*4+2] * kS[p0*4+p2];
      cr += subv[2*4+0] * kS[p2*4+p0];
      cr += subv[0*4+3] * kS[p0*4+p3];
      cr += subv[3*4+0] * kS[p3*4+p0];
      cr += subv[1*4+2] * kS[p1*4+p2];
      cr += subv[2*4+1] * kS[p2*4+p1];
      cr += subv[1*4+3] * kS[p1*4+p3];
      cr += subv[3*4+1] * kS[p3*4+p1];
      maxcr = __builtin_elementwise_max(maxcr, cr);
    }
    v2f best = base0 + lK2[oc] - 2.0f * maxcr;

    int row = (b * COUT + o) * CIN + ci;
    size_t rowbase = (size_t)row * NSUB;
    if (v0) simsOut[rowbase + s0r] = best.x;
    if (v1) simsOut[rowbase + s1r] = best.y;

    // ---- fused per-chunk softmax stats: block max, then sum-exp ----
    float mv = NEGBIG;
    if (v0) mv = best.x;
    if (v1) mv = fmaxf(mv, best.y);
#pragma unroll
    for (int off = 32; off > 0; off >>= 1) mv = fmaxf(mv, __shfl_down(mv, off, 64));
    if (lane == 0) redM[wave] = mv;
    __syncthreads();
    float Mb = fmaxf(fmaxf(redM[0], redM[1]), fmaxf(redM[2], redM[3]));
    float e = 0.f;
    if (v0) e  = __expf(best.x - Mb);
    if (v1) e += __expf(best.y - Mb);
#pragma unroll
    for (int off = 32; off > 0; off >>= 1) e += __shfl_down(e, off, 64);
    if (lane == 0) redS[wave] = e;
    __syncthreads();
    if (t == 0) {
      float2 st;
      st.x = Mb;
      st.y = redS[0] + redS[1] + redS[2] + redS[3];
      ((float2*)partial)[(size_t)row * NCHS + blockIdx.x] = st;
    }
    // redM for next oo is written only after this barrier's release (program
    // order: next best-computation precedes it); reads of redM/redS above are
    // fenced by the two barriers -> no double-buffering needed.
  }
}

// grid (MBF, NROWS): combine 93 (M,S) partials per row + in-place transform.
__global__ __launch_bounds__(256) void softmax_final(float* __restrict__ sims,
                                                     const float* __restrict__ partial) {
  int ch = blockIdx.x, row = blockIdx.y;
  int t = threadIdx.x;

  __shared__ float sM, sInv;
  if (t < 64) {
    const float2* pp = (const float2*)partial + (size_t)row * NCHS;
    float m = NEGBIG, l = 0.f;
    for (int i = t; i < NCHS; i += 64) {
      float2 P = pp[i];
      float M = fmaxf(m, P.x);
      l = l * __expf(m - M) + P.y * __expf(P.x - M);
      m = M;
    }
#pragma unroll
    for (int off = 32; off > 0; off >>= 1) {
      float m2 = __shfl_down(m, off, 64);
      float l2 = __shfl_down(l, off, 64);
      float M = fmaxf(m, m2);
      l = l * __expf(m - M) + l2 * __expf(m2 - M);
      m = M;
    }
    if (t == 0) { sM = m; sInv = 1.0f / l; }
  }
  __syncthreads();
  float M = sM, invS = sInv;

  int base4 = ch * CH4;
  int n4 = NSUB4 - base4; if (n4 > CH4) n4 = CH4;
  float4* rp = (float4*)(sims + (size_t)row * NSUB) + base4;
  const float scale = 1.0f / (float)NSUB;
  for (int i = t; i < n4; i += 256) {
    float4 v = rp[i];
    v.x = (1.0f - __expf(v.x - M) * invS) * scale;
    v.y = (1.0f - __expf(v.y - M) * invS) * scale;
    v.z = (1.0f - __expf(v.z - M) * invS) * scale;
    v.w = (1.0f - __expf(v.w - M) * invS) * scale;
    rp[i] = v;
  }
}

extern "C" void kernel_launch(void* const* d_in, const int* in_sizes, int n_in,
                              void* d_out, int out_size, void* d_ws, size_t ws_size,
                              hipStream_t stream) {
  const float* graph    = (const float*)d_in[0];
  const float* types    = (const float*)d_in[1];
  const float* features = (const float*)d_in[2];
  const float* ks       = (const float*)d_in[3];
  const float* kr       = (const float*)d_in[4];
  const float* kc       = (const float*)d_in[5];
  float* out  = (float*)d_out;
  float* sims = out + B_ * FDIM;

  float* partial = (float*)d_ws;   // NROWS*NCHS*2 floats (~47.6 KB)

  hmean_kernel<<<B_ * FDIM, 64, 0, stream>>>(features, out);
  dim3 sgrid(NCHS, B_ * CIN * OG);
  sims_kernel<<<sgrid, 256, 0, stream>>>(graph, types, ks, kr, kc, sims, partial);
  dim3 fgrid(MBF, NROWS);
  softmax_final<<<fgrid, 256, 0, stream>>>(sims, partial);
}

// Round 5
// 102.709 us; speedup vs baseline: 1.0098x; 1.0098x over previous
//
#include <hip/hip_runtime.h>
#include <hip/hip_bf16.h>

#define B_    2
#define CIN   4
#define COUT  8
#define KK    4
#define DD    2
#define NN    224
#define FDIM  128
#define NH    218
#define NSUB  (NH*NH)         // 47524
#define NPERM 24
#define NROWS (B_*COUT*CIN)   // 64 softmax rows
#define NSUB4 (NSUB/4)        // 11881 float4s per row
#define CH4   512             // float4s per chunk (final transform)
#define MBF   ((NSUB4 + CH4 - 1) / CH4)   // 24 chunk-blocks per row (final)
#define NCHS  ((NSUB + 511) / 512)        // 93 s-chunks (512 s per sims block)
#define NPW   (NCHS * 4)                  // 372 wave-partials per row
#define NEGBIG (-3.4e38f)

typedef float v2f __attribute__((ext_vector_type(2)));

__device__ static constexpr int PERM[NPERM][4] = {
  {0,1,2,3},{0,1,3,2},{0,2,1,3},{0,2,3,1},{0,3,1,2},{0,3,2,1},
  {1,0,2,3},{1,0,3,2},{1,2,0,3},{1,2,3,0},{1,3,0,2},{1,3,2,0},
  {2,0,1,3},{2,0,3,1},{2,1,0,3},{2,1,3,0},{2,3,0,1},{2,3,1,0},
  {3,0,1,2},{3,0,2,1},{3,1,0,2},{3,1,2,0},{3,2,0,1},{3,2,1,0}
};

// one wave per (b,f): lanes split r, shuffle-reduce
__global__ __launch_bounds__(64) void hmean_kernel(const float* __restrict__ features,
                                                   float* __restrict__ out) {
  int bf = blockIdx.x;
  int b = bf / FDIM, f = bf - b * FDIM;
  int lane = threadIdx.x;
  const float* fb = features + (size_t)b * NN * FDIM + f;
  float acc = 0.f;
  for (int r = lane; r < NN; r += 64) {
    int w = 0;
#pragma unroll
    for (int a = 0; a < KK; ++a) {
      int i0 = r - a * DD;
      if (0 <= i0 && i0 < NH) w++;
    }
    acc += (float)w * fb[(size_t)r * FDIM];
  }
#pragma unroll
  for (int off = 32; off > 0; off >>= 1) acc += __shfl_down(acc, off, 64);
  if (lane == 0) out[bf] = acc * (2.0f / (float)NH);
}

// grid: (NCHS, B*CIN). OG=1: each thread gathers subv/rtv/ctv ONCE, then
// loops all 8 o's (halves gather VMEM + addressing vs the OG=2 split).
// Fused softmax stats are WAVE-level (butterfly shfl_xor, zero barriers in
// the o-loop); 4 wave-partials per (row, chunk) -> softmax_final combines
// NPW=372 partials/row. No softmax_partial pass.
__global__ __launch_bounds__(256, 2) void sims_kernel(
    const float* __restrict__ graph, const float* __restrict__ types,
    const float* __restrict__ ksA, const float* __restrict__ krA,
    const float* __restrict__ kcA, float* __restrict__ simsOut,
    float* __restrict__ partial)
{
  __shared__ float ls[COUT * CIN * 16];
  __shared__ float lr[COUT * CIN * 4];
  __shared__ float lc[COUT * CIN * 4];
  __shared__ float lK2[COUT * CIN];
  int t = threadIdx.x;
  for (int i = t; i < COUT * CIN * 16; i += 256) ls[i] = ksA[i];
  for (int i = t; i < COUT * CIN * 4; i += 256) { lr[i] = krA[i]; lc[i] = kcA[i]; }
  __syncthreads();
  if (t < COUT * CIN) {
    float k2 = 0.f;
#pragma unroll
    for (int u = 0; u < 16; ++u) k2 += ls[t * 16 + u] * ls[t * 16 + u];
#pragma unroll
    for (int u = 0; u < 4; ++u) k2 += lr[t * 4 + u] * lr[t * 4 + u] + lc[t * 4 + u] * lc[t * 4 + u];
    lK2[t] = k2;
  }
  __syncthreads();

  int s0r = blockIdx.x * 512 + t;          // always < NSUB (last chunk has 420>256 valid)
  int s1r = s0r + 256;
  bool v1 = (s1r < NSUB);
  int s1 = v1 ? s1r : (NSUB - 1);
  int yi  = blockIdx.y;                    // b*CIN + ci
  int b   = yi >> 2;
  int ci  = yi & 3;
  int ii0 = s0r / NH, jj0 = s0r - ii0 * NH;
  int ii1 = s1 / NH,  jj1 = s1 - ii1 * NH;

  int wave = t >> 6, lane = t & 63;

  const float* gi = graph + ((size_t)b * CIN + ci) * NN * NN;
  const float* ti = types + ((size_t)b * CIN + ci) * NN;

  v2f subv[16], rtv[4], ctv[4];
  v2f G2 = 0.f, T2r = 0.f, T2c = 0.f;
#pragma unroll
  for (int a = 0; a < KK; ++a) {
    const float* r0 = gi + (size_t)(ii0 + a * DD) * NN + jj0;
    const float* r1 = gi + (size_t)(ii1 + a * DD) * NN + jj1;
#pragma unroll
    for (int bb = 0; bb < KK; ++bb) {
      v2f v; v.x = r0[bb * DD]; v.y = r1[bb * DD];
      subv[a * 4 + bb] = v;
      G2 += v * v;
    }
    v2f rv; rv.x = ti[ii0 + a * DD]; rv.y = ti[ii1 + a * DD];
    v2f cv; cv.x = ti[jj0 + a * DD]; cv.y = ti[jj1 + a * DD];
    rtv[a] = rv; ctv[a] = cv;
    T2r += rv * rv; T2c += cv * cv;
  }
  v2f base0 = G2 + T2r + T2c;

#pragma unroll 1
  for (int o = 0; o < COUT; ++o) {
    int oc = o * CIN + ci;
    float kS[16], kR[4], kC[4];
    {
      const float4* pS4 = (const float4*)(ls + oc * 16);
#pragma unroll
      for (int u = 0; u < 4; ++u) {
        float4 q = pS4[u];
        kS[u*4+0] = q.x; kS[u*4+1] = q.y; kS[u*4+2] = q.z; kS[u*4+3] = q.w;
      }
      float4 qr = *(const float4*)(lr + oc * 4);
      kR[0] = qr.x; kR[1] = qr.y; kR[2] = qr.z; kR[3] = qr.w;
      float4 qc = *(const float4*)(lc + oc * 4);
      kC[0] = qc.x; kC[1] = qc.y; kC[2] = qc.z; kC[3] = qc.w;
    }

    // C1[a][a'] = diag + row + col contribution for mapping a->a'
    v2f C1[16];
#pragma unroll
    for (int a = 0; a < 4; ++a)
#pragma unroll
      for (int ap = 0; ap < 4; ++ap)
        C1[a * 4 + ap] = subv[a * 4 + a] * kS[ap * 4 + ap]
                       + rtv[a] * kR[ap] + ctv[a] * kC[ap];

    // pair-DP: pair01[x][y] covers positions {0,1} -> (x,y); pair23 likewise.
    v2f pair01[16], pair23[16];
#pragma unroll
    for (int x = 0; x < 4; ++x)
#pragma unroll
      for (int y = 0; y < 4; ++y) {
        if (x == y) continue;
        pair01[x * 4 + y] = C1[0 * 4 + x] + C1[1 * 4 + y]
                          + subv[0*4+1] * kS[x*4+y] + subv[1*4+0] * kS[y*4+x];
        pair23[x * 4 + y] = C1[2 * 4 + x] + C1[3 * 4 + y]
                          + subv[2*4+3] * kS[x*4+y] + subv[3*4+2] * kS[y*4+x];
      }

    v2f maxcr = NEGBIG;
#pragma unroll
    for (int p = 0; p < NPERM; ++p) {
      const int p0 = PERM[p][0], p1 = PERM[p][1], p2 = PERM[p][2], p3 = PERM[p][3];
      v2f cr = pair01[p0 * 4 + p1] + pair23[p2 * 4 + p3];
      cr += subv[0*4+2] * kS[p0*4+p2];
      cr += subv[2*4+0] * kS[p2*4+p0];
      cr += subv[0*4+3] * kS[p0*4+p3];
      cr += subv[3*4+0] * kS[p3*4+p0];
      cr += subv[1*4+2] * kS[p1*4+p2];
      cr += subv[2*4+1] * kS[p2*4+p1];
      cr += subv[1*4+3] * kS[p1*4+p3];
      cr += subv[3*4+1] * kS[p3*4+p1];
      maxcr = __builtin_elementwise_max(maxcr, cr);
    }
    v2f best = base0 + lK2[oc] - 2.0f * maxcr;

    int row = (b * COUT + o) * CIN + ci;
    size_t rowbase = (size_t)row * NSUB;
    simsOut[rowbase + s0r] = best.x;
    if (v1) simsOut[rowbase + s1r] = best.y;

    // ---- fused wave-level softmax stats (barrier-free butterfly) ----
    float mv = v1 ? fmaxf(best.x, best.y) : best.x;
#pragma unroll
    for (int m = 32; m > 0; m >>= 1) mv = fmaxf(mv, __shfl_xor(mv, m, 64));
    float e = __expf(best.x - mv);
    if (v1) e += __expf(best.y - mv);
#pragma unroll
    for (int m = 32; m > 0; m >>= 1) e += __shfl_xor(e, m, 64);
    if (lane == 0) {
      float2 st; st.x = mv; st.y = e;
      ((float2*)partial)[((size_t)row * NCHS + blockIdx.x) * 4 + wave] = st;
    }
  }
}

// grid (MBF, NROWS): combine 372 (M,S) wave-partials per row + in-place transform.
__global__ __launch_bounds__(256) void softmax_final(float* __restrict__ sims,
                                                     const float* __restrict__ partial) {
  int ch = blockIdx.x, row = blockIdx.y;
  int t = threadIdx.x;

  __shared__ float sM, sInv;
  if (t < 64) {
    const float2* pp = (const float2*)partial + (size_t)row * NPW;
    float m = NEGBIG, l = 0.f;
    for (int i = t; i < NPW; i += 64) {
      float2 P = pp[i];
      float M = fmaxf(m, P.x);
      l = l * __expf(m - M) + P.y * __expf(P.x - M);
      m = M;
    }
#pragma unroll
    for (int off = 32; off > 0; off >>= 1) {
      float m2 = __shfl_down(m, off, 64);
      float l2 = __shfl_down(l, off, 64);
      float M = fmaxf(m, m2);
      l = l * __expf(m - M) + l2 * __expf(m2 - M);
      m = M;
    }
    if (t == 0) { sM = m; sInv = 1.0f / l; }
  }
  __syncthreads();
  float M = sM, invS = sInv;

  int base4 = ch * CH4;
  int n4 = NSUB4 - base4; if (n4 > CH4) n4 = CH4;
  float4* rp = (float4*)(sims + (size_t)row * NSUB) + base4;
  const float scale = 1.0f / (float)NSUB;
  for (int i = t; i < n4; i += 256) {
    float4 v = rp[i];
    v.x = (1.0f - __expf(v.x - M) * invS) * scale;
    v.y = (1.0f - __expf(v.y - M) * invS) * scale;
    v.z = (1.0f - __expf(v.z - M) * invS) * scale;
    v.w = (1.0f - __expf(v.w - M) * invS) * scale;
    rp[i] = v;
  }
}

extern "C" void kernel_launch(void* const* d_in, const int* in_sizes, int n_in,
                              void* d_out, int out_size, void* d_ws, size_t ws_size,
                              hipStream_t stream) {
  const float* graph    = (const float*)d_in[0];
  const float* types    = (const float*)d_in[1];
  const float* features = (const float*)d_in[2];
  const float* ks       = (const float*)d_in[3];
  const float* kr       = (const float*)d_in[4];
  const float* kc       = (const float*)d_in[5];
  float* out  = (float*)d_out;
  float* sims = out + B_ * FDIM;

  float* partial = (float*)d_ws;   // NROWS*NPW float2 (~190 KB)

  hmean_kernel<<<B_ * FDIM, 64, 0, stream>>>(features, out);
  dim3 sgrid(NCHS, B_ * CIN);
  sims_kernel<<<sgrid, 256, 0, stream>>>(graph, types, ks, kr, kc, sims, partial);
  dim3 fgrid(MBF, NROWS);
  softmax_final<<<fgrid, 256, 0, stream>>>(sims, partial);
}

// Round 7
// 101.958 us; speedup vs baseline: 1.0173x; 1.0074x over previous
//
#include <hip/hip_runtime.h>
#include <hip/hip_bf16.h>

#define B_    2
#define CIN   4
#define COUT  8
#define KK    4
#define DD    2
#define NN    224
#define FDIM  128
#define NH    218
#define NSUB  (NH*NH)         // 47524
#define NPERM 24
#define NROWS (B_*COUT*CIN)   // 64 softmax rows
#define NSUB4 (NSUB/4)        // 11881 float4s per row
#define CH4   512             // float4s per chunk (final transform)
#define MBF   ((NSUB4 + CH4 - 1) / CH4)   // 24 chunk-blocks per row (final)
#define NCHS  ((NSUB + 511) / 512)        // 93 s-chunks (512 s per sims block)
#define NPW   (NCHS * 4)                  // 372 wave-partials per row
#define NEGBIG (-3.4e38f)

typedef float v2f __attribute__((ext_vector_type(2)));

__device__ static constexpr int PERM[NPERM][4] = {
  {0,1,2,3},{0,1,3,2},{0,2,1,3},{0,2,3,1},{0,3,1,2},{0,3,2,1},
  {1,0,2,3},{1,0,3,2},{1,2,0,3},{1,2,3,0},{1,3,0,2},{1,3,2,0},
  {2,0,1,3},{2,0,3,1},{2,1,0,3},{2,1,3,0},{2,3,0,1},{2,3,1,0},
  {3,0,1,2},{3,0,2,1},{3,1,0,2},{3,1,2,0},{3,2,0,1},{3,2,1,0}
};

// grid: (NCHS, B*CIN) x 256. Each thread: s0 = blk*512+t, s1 = s0+256 packed
// as v2f; all 8 o's per thread (pair-DP perm loop); wave-level fused softmax
// stats (barrier-free butterfly) -> 4 wave-partials per (row, chunk).
// hmean FOLDED in: wave 0 of blocks c<32 computes one (b,f) row-sum each
// (256 pairs exactly) -- independent side-work hidden under sims compute.
// NOTE: cooperative-launch fusion (R6) never executed under the harness's
// graph capture (output stayed zero) -- do NOT use hipLaunchCooperativeKernel.
__global__ __launch_bounds__(256, 2) void sims_kernel(
    const float* __restrict__ graph, const float* __restrict__ types,
    const float* __restrict__ ksA, const float* __restrict__ krA,
    const float* __restrict__ kcA, const float* __restrict__ features,
    float* __restrict__ out, float* __restrict__ simsOut,
    float* __restrict__ partial)
{
  __shared__ float ls[COUT * CIN * 16];
  __shared__ float lr[COUT * CIN * 4];
  __shared__ float lc[COUT * CIN * 4];
  __shared__ float lK2[COUT * CIN];
  int t = threadIdx.x;
  int wave = t >> 6, lane = t & 63;
  int c  = blockIdx.x;
  int yi = blockIdx.y;                 // b*CIN + ci
  int b  = yi >> 2;
  int ci = yi & 3;

  // ---- folded hmean: wave 0 of blocks c<32; bf = c*8+yi covers 0..255 ----
  if (c < 32 && wave == 0) {
    int bf = c * 8 + yi;
    int bb = bf >> 7;                  // bf / FDIM
    int f  = bf & (FDIM - 1);
    const float* fb = features + (size_t)bb * NN * FDIM + f;
    float acc = 0.f;
    for (int r = lane; r < NN; r += 64) {
      int w = 0;
#pragma unroll
      for (int a = 0; a < KK; ++a) {
        int i0 = r - a * DD;
        if (0 <= i0 && i0 < NH) w++;
      }
      acc += (float)w * fb[(size_t)r * FDIM];
    }
#pragma unroll
    for (int off = 32; off > 0; off >>= 1) acc += __shfl_down(acc, off, 64);
    if (lane == 0) out[bf] = acc * (2.0f / (float)NH);
  }

  for (int i = t; i < COUT * CIN * 16; i += 256) ls[i] = ksA[i];
  for (int i = t; i < COUT * CIN * 4; i += 256) { lr[i] = krA[i]; lc[i] = kcA[i]; }
  __syncthreads();
  if (t < COUT * CIN) {
    float k2 = 0.f;
#pragma unroll
    for (int u = 0; u < 16; ++u) k2 += ls[t * 16 + u] * ls[t * 16 + u];
#pragma unroll
    for (int u = 0; u < 4; ++u) k2 += lr[t * 4 + u] * lr[t * 4 + u] + lc[t * 4 + u] * lc[t * 4 + u];
    lK2[t] = k2;
  }
  __syncthreads();

  int s0r = c * 512 + t;               // always < NSUB (last chunk: 420 valid > 256)
  int s1r = s0r + 256;
  bool v1 = (s1r < NSUB);
  int s1 = v1 ? s1r : (NSUB - 1);
  int ii0 = s0r / NH, jj0 = s0r - ii0 * NH;
  int ii1 = s1 / NH,  jj1 = s1 - ii1 * NH;

  const float* gi = graph + ((size_t)b * CIN + ci) * NN * NN;
  const float* ti = types + ((size_t)b * CIN + ci) * NN;

  v2f subv[16], rtv[4], ctv[4];
  v2f G2 = 0.f, T2r = 0.f, T2c = 0.f;
#pragma unroll
  for (int a = 0; a < KK; ++a) {
    const float* r0 = gi + (size_t)(ii0 + a * DD) * NN + jj0;
    const float* r1 = gi + (size_t)(ii1 + a * DD) * NN + jj1;
#pragma unroll
    for (int bb = 0; bb < KK; ++bb) {
      v2f v; v.x = r0[bb * DD]; v.y = r1[bb * DD];
      subv[a * 4 + bb] = v;
      G2 += v * v;
    }
    v2f rv; rv.x = ti[ii0 + a * DD]; rv.y = ti[ii1 + a * DD];
    v2f cv; cv.x = ti[jj0 + a * DD]; cv.y = ti[jj1 + a * DD];
    rtv[a] = rv; ctv[a] = cv;
    T2r += rv * rv; T2c += cv * cv;
  }
  v2f base0 = G2 + T2r + T2c;

#pragma unroll 1
  for (int o = 0; o < COUT; ++o) {
    int oc = o * CIN + ci;
    float kS[16], kR[4], kC[4];
    {
      const float4* pS4 = (const float4*)(ls + oc * 16);
#pragma unroll
      for (int u = 0; u < 4; ++u) {
        float4 q = pS4[u];
        kS[u*4+0] = q.x; kS[u*4+1] = q.y; kS[u*4+2] = q.z; kS[u*4+3] = q.w;
      }
      float4 qr = *(const float4*)(lr + oc * 4);
      kR[0] = qr.x; kR[1] = qr.y; kR[2] = qr.z; kR[3] = qr.w;
      float4 qc = *(const float4*)(lc + oc * 4);
      kC[0] = qc.x; kC[1] = qc.y; kC[2] = qc.z; kC[3] = qc.w;
    }

    // C1[a][a'] = diag + row + col contribution for mapping a->a'
    v2f C1[16];
#pragma unroll
    for (int a = 0; a < 4; ++a)
#pragma unroll
      for (int ap = 0; ap < 4; ++ap)
        C1[a * 4 + ap] = subv[a * 4 + a] * kS[ap * 4 + ap]
                       + rtv[a] * kR[ap] + ctv[a] * kC[ap];

    // pair-DP: pair01[x][y] covers positions {0,1} -> (x,y); pair23 likewise.
    v2f pair01[16], pair23[16];
#pragma unroll
    for (int x = 0; x < 4; ++x)
#pragma unroll
      for (int y = 0; y < 4; ++y) {
        if (x == y) continue;
        pair01[x * 4 + y] = C1[0 * 4 + x] + C1[1 * 4 + y]
                          + subv[0*4+1] * kS[x*4+y] + subv[1*4+0] * kS[y*4+x];
        pair23[x * 4 + y] = C1[2 * 4 + x] + C1[3 * 4 + y]
                          + subv[2*4+3] * kS[x*4+y] + subv[3*4+2] * kS[y*4+x];
      }

    v2f maxcr = NEGBIG;
#pragma unroll
    for (int p = 0; p < NPERM; ++p) {
      const int p0 = PERM[p][0], p1 = PERM[p][1], p2 = PERM[p][2], p3 = PERM[p][3];
      v2f cr = pair01[p0 * 4 + p1] + pair23[p2 * 4 + p3];
      cr += subv[0*4+2] * kS[p0*4+p2];
      cr += subv[2*4+0] * kS[p2*4+p0];
      cr += subv[0*4+3] * kS[p0*4+p3];
      cr += subv[3*4+0] * kS[p3*4+p0];
      cr += subv[1*4+2] * kS[p1*4+p2];
      cr += subv[2*4+1] * kS[p2*4+p1];
      cr += subv[1*4+3] * kS[p1*4+p3];
      cr += subv[3*4+1] * kS[p3*4+p1];
      maxcr = __builtin_elementwise_max(maxcr, cr);
    }
    v2f best = base0 + lK2[oc] - 2.0f * maxcr;

    int row = (b * COUT + o) * CIN + ci;
    size_t rowbase = (size_t)row * NSUB;
    simsOut[rowbase + s0r] = best.x;
    if (v1) simsOut[rowbase + s1r] = best.y;

    // ---- fused wave-level softmax stats (barrier-free butterfly) ----
    float mv = v1 ? fmaxf(best.x, best.y) : best.x;
#pragma unroll
    for (int m = 32; m > 0; m >>= 1) mv = fmaxf(mv, __shfl_xor(mv, m, 64));
    float e = __expf(best.x - mv);
    if (v1) e += __expf(best.y - mv);
#pragma unroll
    for (int m = 32; m > 0; m >>= 1) e += __shfl_xor(e, m, 64);
    if (lane == 0) {
      float2 st; st.x = mv; st.y = e;
      ((float2*)partial)[((size_t)row * NCHS + c) * 4 + wave] = st;
    }
  }
}

// grid (MBF, NROWS): combine 372 (M,S) wave-partials per row + in-place transform.
__global__ __launch_bounds__(256) void softmax_final(float* __restrict__ sims,
                                                     const float* __restrict__ partial) {
  int ch = blockIdx.x, row = blockIdx.y;
  int t = threadIdx.x;

  __shared__ float sM, sInv;
  if (t < 64) {
    const float2* pp = (const float2*)partial + (size_t)row * NPW;
    float m = NEGBIG, l = 0.f;
    for (int i = t; i < NPW; i += 64) {
      float2 P = pp[i];
      float M = fmaxf(m, P.x);
      l = l * __expf(m - M) + P.y * __expf(P.x - M);
      m = M;
    }
#pragma unroll
    for (int off = 32; off > 0; off >>= 1) {
      float m2 = __shfl_down(m, off, 64);
      float l2 = __shfl_down(l, off, 64);
      float M = fmaxf(m, m2);
      l = l * __expf(m - M) + l2 * __expf(m2 - M);
      m = M;
    }
    if (t == 0) { sM = m; sInv = 1.0f / l; }
  }
  __syncthreads();
  float M = sM, invS = sInv;

  int base4 = ch * CH4;
  int n4 = NSUB4 - base4; if (n4 > CH4) n4 = CH4;
  float4* rp = (float4*)(sims + (size_t)row * NSUB) + base4;
  const float scale = 1.0f / (float)NSUB;
  for (int i = t; i < n4; i += 256) {
    float4 v = rp[i];
    v.x = (1.0f - __expf(v.x - M) * invS) * scale;
    v.y = (1.0f - __expf(v.y - M) * invS) * scale;
    v.z = (1.0f - __expf(v.z - M) * invS) * scale;
    v.w = (1.0f - __expf(v.w - M) * invS) * scale;
    rp[i] = v;
  }
}

extern "C" void kernel_launch(void* const* d_in, const int* in_sizes, int n_in,
                              void* d_out, int out_size, void* d_ws, size_t ws_size,
                              hipStream_t stream) {
  const float* graph    = (const float*)d_in[0];
  const float* types    = (const float*)d_in[1];
  const float* features = (const float*)d_in[2];
  const float* ks       = (const float*)d_in[3];
  const float* kr       = (const float*)d_in[4];
  const float* kc       = (const float*)d_in[5];
  float* out  = (float*)d_out;
  float* sims = out + B_ * FDIM;

  float* partial = (float*)d_ws;   // NROWS*NPW float2 (~190 KB)

  dim3 sgrid(NCHS, B_ * CIN);
  sims_kernel<<<sgrid, 256, 0, stream>>>(graph, types, ks, kr, kc,
                                         features, out, sims, partial);
  dim3 fgrid(MBF, NROWS);
  softmax_final<<<fgrid, 256, 0, stream>>>(sims, partial);
}